// Round 7
// baseline (677.265 us; speedup 1.0000x reference)
//
#include <hip/hip_runtime.h>

#define BB 1024
#define TT 2048
#define NIN 8
#define NHI 64

#define CS 2.8853900817779268f      /* 2*log2(e) */
#define ICS (1.0f / CS)
#define NL2E 1.4426950408889634f    /* log2(e) */
#define DELTA (40.94f / 2047.0f)

// exact sigmoid on prescaled arg: zs = -log2e*z -> 1/(1+exp2(zs))
__device__ __forceinline__ float sig_pre(float zs) {
    float e = __builtin_amdgcn_exp2f(zs);
    return __builtin_amdgcn_rcpf(1.0f + e);
}

template<int CTRL>
__device__ __forceinline__ float qperm(float x) {
    int r = __builtin_amdgcn_mov_dpp(__float_as_int(x), CTRL, 0xF, 0xF, true);
    return __int_as_float(r);
}

// ---------------- precompute g = h*r records [b][s][{gg,ga,gc}] -------------
// Weights read directly from global (uniform per j -> s_load, scalar pipe).
// Interior-stage exponentials via shared-exp: e1 = e0*edz, e2 = e1*edz.
__global__ __launch_bounds__(256) void precompute_r(
    const float* __restrict__ u, const float* __restrict__ Wni,
    const float* __restrict__ bni, const float* __restrict__ Wli,
    const float* __restrict__ bli, const float* __restrict__ tau,
    float* __restrict__ r3)
{
    int lt = threadIdx.x;
    int lane = lt & 63;
    long long gw = (long long)blockIdx.x * 4 + (lt >> 6);   // 1024*33 waves
    int b = (int)(gw / 33);
    int chunk = (int)(gw % 33);
    int s = chunk * 63 + lane;
    int sc = s < TT ? s : TT - 1;

    const float4* up4 = reinterpret_cast<const float4*>(u + ((long long)b * TT + sc) * NIN);
    float4 uA = up4[0], uB = up4[1];

    float d0 = 0.f, d1 = 0.f, d2 = 0.f;
    #pragma unroll 8
    for (int j = 0; j < NHI; j++) {
        const float* wj = Wni + j * NIN;          // uniform -> scalar loads
        float z = bni[j];
        z = fmaf(wj[0], uA.x, z); z = fmaf(wj[1], uA.y, z);
        z = fmaf(wj[2], uA.z, z); z = fmaf(wj[3], uA.w, z);
        z = fmaf(wj[4], uB.x, z); z = fmaf(wj[5], uB.y, z);
        z = fmaf(wj[6], uB.z, z); z = fmaf(wj[7], uB.w, z);
        float zn = __shfl_down(z, 1);
        float dz = zn - z;
        float e0  = __builtin_amdgcn_exp2f(z * -NL2E);
        float edz = __builtin_amdgcn_exp2f(dz * (-NL2E / 3.0f));
        float e1 = e0 * edz;
        float e2 = e1 * edz;
        float wl = Wli[j];
        d0 = fmaf(wl, __builtin_amdgcn_rcpf(1.0f + e0), d0);
        d1 = fmaf(wl, __builtin_amdgcn_rcpf(1.0f + e1), d1);
        d2 = fmaf(wl, __builtin_amdgcn_rcpf(1.0f + e2), d2);
    }
    float base = tau[0] + bli[0];
    // store g = h*r (pre-scaled) so the scan needs no h multiplies
    float g0 = DELTA * __builtin_amdgcn_exp2f((base + d0) * -NL2E);
    float g1 = DELTA * __builtin_amdgcn_exp2f((base + d1) * -NL2E);
    float g2 = DELTA * __builtin_amdgcn_exp2f((base + d2) * -NL2E);

    if (s < TT) {
        float* p = r3 + ((long long)b * TT + s) * 3;
        p[0] = g0;
        if (lane < 63 && s < TT - 1) { p[1] = g1; p[2] = g2; }
    }
}

// ---------------- sequential RK4 scan: one b per quad, lane = component -----
// Scaled state X = CS*x; records hold g = h*r. Per-stage chain:
// exp2 -> add1 -> rcp -> dpp -> fma -> fma.
// 512-thread blocks: 8 waves/CU -> 2 waves/SIMD, so a second independent
// chain fills each wave's trans-latency stall gaps.
__global__ __launch_bounds__(512) void scan_kernel(
    const float* __restrict__ r3, float* __restrict__ xs)
{
    int gt = blockIdx.x * 512 + threadIdx.x;    // 4096 threads
    int b = gt >> 2;
    int l = gt & 3;

    const float4* rp = reinterpret_cast<const float4*>(r3 + (long long)b * TT * 3);
    int comp = (l == 3) ? 1 : l;
    float* xc = xs + (long long)comp * BB * TT + (long long)b * TT;

    bool is2 = (l == 2);
    float cA = is2 ? 40.0f * CS : -2.0f * CS;
    float cB = is2 ? -20.0f * CS : 0.0f;
    float Kl = is2 ? -10.0f * CS : CS;

    float X = (l == 0) ? 0.4736f * CS : (is2 ? 1.8497f * CS : 0.8745f * CS);

#define STEP(G1v, G2v, G3v, G4v) do { \
    float g1 = (G1v), g2 = (G2v), g3 = (G3v); \
    float q  = g1 * (1.0f / 3.0f); \
    float g4_8 = (G4v) * 0.125f; \
    float cA1 = q * cA,    cB1 = q * cB; \
    float cA2 = g2 * cA,   cB2 = g2 * cB; \
    float cA3 = g3 * cA,   cB3 = g3 * cB; \
    float cA4 = g4_8 * cA, cB4 = g4_8 * cB; \
    /* stage 1 */ \
    float e1 = __builtin_amdgcn_exp2f(X); \
    float rho1 = __builtin_amdgcn_rcpf(1.0f + e1); \
    float KmX = Kl - X; \
    float pb2 = fmaf(q, KmX, X); \
    float p11 = qperm<0x89>(rho1), p21 = qperm<0x10>(rho1); \
    float S2 = fmaf(cA1, p11, fmaf(cB1, p21, pb2)); \
    float V1 = fmaf(cA, p11, cB * p21); \
    float W1 = V1 + KmX; \
    /* stage 2 */ \
    float e2 = __builtin_amdgcn_exp2f(S2); \
    float rho2 = __builtin_amdgcn_rcpf(1.0f + e2); \
    float KmS2 = Kl - S2; \
    float pb3 = fmaf(g2, KmS2, fmaf(-q, W1, X)); \
    float p12 = qperm<0x89>(rho2), p22 = qperm<0x10>(rho2); \
    float S3 = fmaf(cA2, p12, fmaf(cB2, p22, pb3)); \
    float V2 = fmaf(cA, p12, cB * p22); \
    float W2 = V2 + KmS2; \
    /* stage 3 */ \
    float e3 = __builtin_amdgcn_exp2f(S3); \
    float rho3 = __builtin_amdgcn_rcpf(1.0f + e3); \
    float KmS3 = Kl - S3; \
    float pb4 = fmaf(g3, KmS3, fmaf(-g2, W2, fmaf(g1, W1, X))); \
    float p13 = qperm<0x89>(rho3), p23 = qperm<0x10>(rho3); \
    float S4 = fmaf(cA3, p13, fmaf(cB3, p23, pb4)); \
    float V3 = fmaf(cA, p13, cB * p23); \
    float W3 = V3 + KmS3; \
    /* stage 4 */ \
    float e4 = __builtin_amdgcn_exp2f(S4); \
    float rho4 = __builtin_amdgcn_rcpf(1.0f + e4); \
    float KmS4 = Kl - S4; \
    float t3 = fmaf(3.0f * g3, W3, fmaf(3.0f * g2, W2, g1 * W1)); \
    float pbX = fmaf(g4_8, KmS4, fmaf(0.125f, t3, X)); \
    float p14 = qperm<0x89>(rho4), p24 = qperm<0x10>(rho4); \
    X = fmaf(cA4, p14, fmaf(cB4, p24, pbX)); \
} while (0)

    float4 f0 = rp[0], f1 = rp[1], f2 = rp[2];
    float4 n0 = rp[3], n1 = rp[4], n2 = rp[5];

    for (int j = 0; j < 510; j++) {
        float4 m0 = rp[3 * j + 6], m1 = rp[3 * j + 7], m2 = rp[3 * j + 8];
        float4 ov;
        ov.x = X * ICS;
        STEP(f0.x, f0.y, f0.z, f0.w);  ov.y = X * ICS;
        STEP(f0.w, f1.x, f1.y, f1.z);  ov.z = X * ICS;
        STEP(f1.z, f1.w, f2.x, f2.y);  ov.w = X * ICS;
        *reinterpret_cast<float4*>(xc + 4 * j) = ov;
        STEP(f2.y, f2.z, f2.w, n0.x);
        f0 = n0; f1 = n1; f2 = n2;
        n0 = m0; n1 = m1; n2 = m2;
    }
    {   // chunk 510 (steps 2040..2043)
        float4 ov;
        ov.x = X * ICS;
        STEP(f0.x, f0.y, f0.z, f0.w);  ov.y = X * ICS;
        STEP(f0.w, f1.x, f1.y, f1.z);  ov.z = X * ICS;
        STEP(f1.z, f1.w, f2.x, f2.y);  ov.w = X * ICS;
        *reinterpret_cast<float4*>(xc + 4 * 510) = ov;
        STEP(f2.y, f2.z, f2.w, n0.x);
        f0 = n0; f1 = n1; f2 = n2;
    }
    {   // chunk 511 (steps 2044..2046 -> X(2045..2047))
        float4 ov;
        ov.x = X * ICS;
        STEP(f0.x, f0.y, f0.z, f0.w);  ov.y = X * ICS;
        STEP(f0.w, f1.x, f1.y, f1.z);  ov.z = X * ICS;
        STEP(f1.z, f1.w, f2.x, f2.y);  ov.w = X * ICS;
        *reinterpret_cast<float4*>(xc + 4 * 511) = ov;
    }
#undef STEP
}

// ---------------- readout: out = sigmoid(x @ Wn^T + bn) @ Wl^T + bl --------
// Weights read directly from global (uniform per j -> s_load, scalar pipe).
__global__ __launch_bounds__(256) void out_kernel(
    const float* __restrict__ xs, const float* __restrict__ Wn,
    const float* __restrict__ bn, const float* __restrict__ Wl,
    const float* __restrict__ bl, float* __restrict__ out)
{
    int lt = threadIdx.x;
    long long tid = (long long)blockIdx.x * 256 + lt;   // tid = b*T + t
    float c0 = xs[tid];
    float c1 = xs[(long long)BB * TT + tid];
    float c2 = xs[(long long)2 * BB * TT + tid];
    float cs0 = c0 * -NL2E, cs1 = c1 * -NL2E, cs2 = c2 * -NL2E;
    float acc = 0.0f;
    #pragma unroll 8
    for (int j = 0; j < NHI; j++) {
        float zs = fmaf(Wn[j * 3], cs0,
                   fmaf(Wn[j * 3 + 1], cs1,
                   fmaf(Wn[j * 3 + 2], cs2, bn[j] * -NL2E)));
        acc = fmaf(Wl[j], sig_pre(zs), acc);
    }
    out[tid] = acc + bl[0];
}

extern "C" void kernel_launch(void* const* d_in, const int* in_sizes, int n_in,
                              void* d_out, int out_size, void* d_ws, size_t ws_size,
                              hipStream_t stream) {
    const float* u    = (const float*)d_in[0];
    const float* Wni  = (const float*)d_in[1];
    const float* bni  = (const float*)d_in[2];
    const float* Wli  = (const float*)d_in[3];
    const float* bli  = (const float*)d_in[4];
    const float* tau  = (const float*)d_in[5];
    const float* Wn   = (const float*)d_in[6];
    const float* bn   = (const float*)d_in[7];
    const float* Wl   = (const float*)d_in[8];
    const float* bl   = (const float*)d_in[9];
    float* out = (float*)d_out;

    float* r3 = (float*)d_ws;                          // B*T*3 floats (24 MB)
    float* xs = r3 + (size_t)3 * BB * TT;              // [3][B][T] (24 MB)

    precompute_r<<<(BB * 33) / 4, 256, 0, stream>>>(u, Wni, bni, Wli, bli, tau, r3);
    scan_kernel<<<(BB * 4) / 512, 512, 0, stream>>>(r3, xs);
    out_kernel<<<(BB * TT) / 256, 256, 0, stream>>>(xs, Wn, bn, Wl, bl, out);
}

// Round 8
// 590.826 us; speedup vs baseline: 1.1463x; 1.1463x over previous
//
#include <hip/hip_runtime.h>

#define BB 1024
#define TT 2048
#define NIN 8
#define NHI 64

#define CS 2.8853900817779268f      /* 2*log2(e) */
#define ICS (1.0f / CS)
#define NL2E 1.4426950408889634f    /* log2(e) */
#define DELTA (40.94f / 2047.0f)

// exact sigmoid on prescaled arg: zs = -log2e*z -> 1/(1+exp2(zs))
__device__ __forceinline__ float sig_pre(float zs) {
    float e = __builtin_amdgcn_exp2f(zs);
    return __builtin_amdgcn_rcpf(1.0f + e);
}

template<int CTRL>
__device__ __forceinline__ float qperm(float x) {
    int r = __builtin_amdgcn_mov_dpp(__float_as_int(x), CTRL, 0xF, 0xF, true);
    return __int_as_float(r);
}

// ---------------- precompute g = h*r records [b][s][{gg,ga,gc}] -------------
// Weights read directly from global (uniform per j -> s_load, scalar pipe).
// Interior-stage exponentials via shared-exp: e1 = e0*edz, e2 = e1*edz.
__global__ __launch_bounds__(256) void precompute_r(
    const float* __restrict__ u, const float* __restrict__ Wni,
    const float* __restrict__ bni, const float* __restrict__ Wli,
    const float* __restrict__ bli, const float* __restrict__ tau,
    float* __restrict__ r3)
{
    int lt = threadIdx.x;
    int lane = lt & 63;
    long long gw = (long long)blockIdx.x * 4 + (lt >> 6);   // 1024*33 waves
    int b = (int)(gw / 33);
    int chunk = (int)(gw % 33);
    int s = chunk * 63 + lane;
    int sc = s < TT ? s : TT - 1;

    const float4* up4 = reinterpret_cast<const float4*>(u + ((long long)b * TT + sc) * NIN);
    float4 uA = up4[0], uB = up4[1];

    float d0 = 0.f, d1 = 0.f, d2 = 0.f;
    #pragma unroll 8
    for (int j = 0; j < NHI; j++) {
        const float* wj = Wni + j * NIN;          // uniform -> scalar loads
        float z = bni[j];
        z = fmaf(wj[0], uA.x, z); z = fmaf(wj[1], uA.y, z);
        z = fmaf(wj[2], uA.z, z); z = fmaf(wj[3], uA.w, z);
        z = fmaf(wj[4], uB.x, z); z = fmaf(wj[5], uB.y, z);
        z = fmaf(wj[6], uB.z, z); z = fmaf(wj[7], uB.w, z);
        float zn = __shfl_down(z, 1);
        float dz = zn - z;
        float e0  = __builtin_amdgcn_exp2f(z * -NL2E);
        float edz = __builtin_amdgcn_exp2f(dz * (-NL2E / 3.0f));
        float e1 = e0 * edz;
        float e2 = e1 * edz;
        float wl = Wli[j];
        d0 = fmaf(wl, __builtin_amdgcn_rcpf(1.0f + e0), d0);
        d1 = fmaf(wl, __builtin_amdgcn_rcpf(1.0f + e1), d1);
        d2 = fmaf(wl, __builtin_amdgcn_rcpf(1.0f + e2), d2);
    }
    float base = tau[0] + bli[0];
    float g0 = DELTA * __builtin_amdgcn_exp2f((base + d0) * -NL2E);
    float g1 = DELTA * __builtin_amdgcn_exp2f((base + d1) * -NL2E);
    float g2 = DELTA * __builtin_amdgcn_exp2f((base + d2) * -NL2E);

    if (s < TT) {
        float* p = r3 + ((long long)b * TT + s) * 3;
        p[0] = g0;
        if (lane < 63 && s < TT - 1) { p[1] = g1; p[2] = g2; }
    }
}

// ---------------- sequential RK4 scan: 2 batches per lane, ILP-paired -------
// Scaled state X = CS*x; records hold g = h*r. Per-stage chain:
// exp2 -> add1 -> rcp -> dpp -> fma -> fma. Two independent chains (batch
// q and q+512) interleaved stage-by-stage in one instruction stream so each
// chain's trans latency is filled by the other's issue. 64-thr blocks,
// 1 wave/SIMD (the proven geometry; r7 showed 2 waves/SIMD serialize).
__global__ __launch_bounds__(64) void scan_kernel(
    const float* __restrict__ r3, float* __restrict__ xs)
{
    int gt = blockIdx.x * 64 + threadIdx.x;     // 2048 threads
    int q = gt >> 2;                            // quad id 0..511
    int l = gt & 3;
    int bA = q;
    int bB = q + 512;

    const float4* rpA = reinterpret_cast<const float4*>(r3 + (long long)bA * TT * 3);
    const float4* rpB = reinterpret_cast<const float4*>(r3 + (long long)bB * TT * 3);
    int comp = (l == 3) ? 1 : l;
    float* xcA = xs + (long long)comp * BB * TT + (long long)bA * TT;
    float* xcB = xs + (long long)comp * BB * TT + (long long)bB * TT;

    bool is2 = (l == 2);
    float cA = is2 ? 40.0f * CS : -2.0f * CS;
    float cB = is2 ? -20.0f * CS : 0.0f;
    float Kl = is2 ? -10.0f * CS : CS;

    float X0i = (l == 0) ? 0.4736f * CS : (is2 ? 1.8497f * CS : 0.8745f * CS);
    float XA = X0i, XB = X0i;

#define STEP2(GA1, GA2, GA3, GA4, GB1, GB2, GB3, GB4) do { \
    float g1A = (GA1), g2A = (GA2), g3A = (GA3); \
    float g1B = (GB1), g2B = (GB2), g3B = (GB3); \
    float qA = g1A * (1.0f / 3.0f), qB = g1B * (1.0f / 3.0f); \
    float g48A = (GA4) * 0.125f, g48B = (GB4) * 0.125f; \
    float cA1A = qA * cA,   cB1A = qA * cB; \
    float cA1B = qB * cA,   cB1B = qB * cB; \
    float cA2A = g2A * cA,  cB2A = g2A * cB; \
    float cA2B = g2B * cA,  cB2B = g2B * cB; \
    float cA3A = g3A * cA,  cB3A = g3A * cB; \
    float cA3B = g3B * cA,  cB3B = g3B * cB; \
    float cA4A = g48A * cA, cB4A = g48A * cB; \
    float cA4B = g48B * cA, cB4B = g48B * cB; \
    /* ---- stage 1 (A|B interleaved) ---- */ \
    float e1A = __builtin_amdgcn_exp2f(XA); \
    float e1B = __builtin_amdgcn_exp2f(XB); \
    float rho1A = __builtin_amdgcn_rcpf(1.0f + e1A); \
    float rho1B = __builtin_amdgcn_rcpf(1.0f + e1B); \
    float KmXA = Kl - XA,               KmXB = Kl - XB; \
    float pb2A = fmaf(qA, KmXA, XA),    pb2B = fmaf(qB, KmXB, XB); \
    float p11A = qperm<0x89>(rho1A),    p21A = qperm<0x10>(rho1A); \
    float p11B = qperm<0x89>(rho1B),    p21B = qperm<0x10>(rho1B); \
    float S2A = fmaf(cA1A, p11A, fmaf(cB1A, p21A, pb2A)); \
    float S2B = fmaf(cA1B, p11B, fmaf(cB1B, p21B, pb2B)); \
    float V1A = fmaf(cA, p11A, cB * p21A), V1B = fmaf(cA, p11B, cB * p21B); \
    float W1A = V1A + KmXA,             W1B = V1B + KmXB; \
    /* ---- stage 2 ---- */ \
    float e2A = __builtin_amdgcn_exp2f(S2A); \
    float e2B = __builtin_amdgcn_exp2f(S2B); \
    float rho2A = __builtin_amdgcn_rcpf(1.0f + e2A); \
    float rho2B = __builtin_amdgcn_rcpf(1.0f + e2B); \
    float KmS2A = Kl - S2A,             KmS2B = Kl - S2B; \
    float pb3A = fmaf(g2A, KmS2A, fmaf(-qA, W1A, XA)); \
    float pb3B = fmaf(g2B, KmS2B, fmaf(-qB, W1B, XB)); \
    float p12A = qperm<0x89>(rho2A),    p22A = qperm<0x10>(rho2A); \
    float p12B = qperm<0x89>(rho2B),    p22B = qperm<0x10>(rho2B); \
    float S3A = fmaf(cA2A, p12A, fmaf(cB2A, p22A, pb3A)); \
    float S3B = fmaf(cA2B, p12B, fmaf(cB2B, p22B, pb3B)); \
    float V2A = fmaf(cA, p12A, cB * p22A), V2B = fmaf(cA, p12B, cB * p22B); \
    float W2A = V2A + KmS2A,            W2B = V2B + KmS2B; \
    /* ---- stage 3 ---- */ \
    float e3A = __builtin_amdgcn_exp2f(S3A); \
    float e3B = __builtin_amdgcn_exp2f(S3B); \
    float rho3A = __builtin_amdgcn_rcpf(1.0f + e3A); \
    float rho3B = __builtin_amdgcn_rcpf(1.0f + e3B); \
    float KmS3A = Kl - S3A,             KmS3B = Kl - S3B; \
    float pb4A = fmaf(g3A, KmS3A, fmaf(-g2A, W2A, fmaf(g1A, W1A, XA))); \
    float pb4B = fmaf(g3B, KmS3B, fmaf(-g2B, W2B, fmaf(g1B, W1B, XB))); \
    float p13A = qperm<0x89>(rho3A),    p23A = qperm<0x10>(rho3A); \
    float p13B = qperm<0x89>(rho3B),    p23B = qperm<0x10>(rho3B); \
    float S4A = fmaf(cA3A, p13A, fmaf(cB3A, p23A, pb4A)); \
    float S4B = fmaf(cA3B, p13B, fmaf(cB3B, p23B, pb4B)); \
    float V3A = fmaf(cA, p13A, cB * p23A), V3B = fmaf(cA, p13B, cB * p23B); \
    float W3A = V3A + KmS3A,            W3B = V3B + KmS3B; \
    /* ---- stage 4 ---- */ \
    float e4A = __builtin_amdgcn_exp2f(S4A); \
    float e4B = __builtin_amdgcn_exp2f(S4B); \
    float rho4A = __builtin_amdgcn_rcpf(1.0f + e4A); \
    float rho4B = __builtin_amdgcn_rcpf(1.0f + e4B); \
    float KmS4A = Kl - S4A,             KmS4B = Kl - S4B; \
    float t3A = fmaf(3.0f * g3A, W3A, fmaf(3.0f * g2A, W2A, g1A * W1A)); \
    float t3B = fmaf(3.0f * g3B, W3B, fmaf(3.0f * g2B, W2B, g1B * W1B)); \
    float pbXA = fmaf(g48A, KmS4A, fmaf(0.125f, t3A, XA)); \
    float pbXB = fmaf(g48B, KmS4B, fmaf(0.125f, t3B, XB)); \
    float p14A = qperm<0x89>(rho4A),    p24A = qperm<0x10>(rho4A); \
    float p14B = qperm<0x89>(rho4B),    p24B = qperm<0x10>(rho4B); \
    XA = fmaf(cA4A, p14A, fmaf(cB4A, p24A, pbXA)); \
    XB = fmaf(cA4B, p14B, fmaf(cB4B, p24B, pbXB)); \
} while (0)

    float4 f0A = rpA[0], f1A = rpA[1], f2A = rpA[2];
    float4 n0A = rpA[3], n1A = rpA[4], n2A = rpA[5];
    float4 f0B = rpB[0], f1B = rpB[1], f2B = rpB[2];
    float4 n0B = rpB[3], n1B = rpB[4], n2B = rpB[5];

    for (int j = 0; j < 510; j++) {
        float4 m0A = rpA[3 * j + 6], m1A = rpA[3 * j + 7], m2A = rpA[3 * j + 8];
        float4 m0B = rpB[3 * j + 6], m1B = rpB[3 * j + 7], m2B = rpB[3 * j + 8];
        float4 ovA, ovB;
        ovA.x = XA * ICS; ovB.x = XB * ICS;
        STEP2(f0A.x, f0A.y, f0A.z, f0A.w,  f0B.x, f0B.y, f0B.z, f0B.w);
        ovA.y = XA * ICS; ovB.y = XB * ICS;
        STEP2(f0A.w, f1A.x, f1A.y, f1A.z,  f0B.w, f1B.x, f1B.y, f1B.z);
        ovA.z = XA * ICS; ovB.z = XB * ICS;
        STEP2(f1A.z, f1A.w, f2A.x, f2A.y,  f1B.z, f1B.w, f2B.x, f2B.y);
        ovA.w = XA * ICS; ovB.w = XB * ICS;
        *reinterpret_cast<float4*>(xcA + 4 * j) = ovA;
        *reinterpret_cast<float4*>(xcB + 4 * j) = ovB;
        STEP2(f2A.y, f2A.z, f2A.w, n0A.x,  f2B.y, f2B.z, f2B.w, n0B.x);
        f0A = n0A; f1A = n1A; f2A = n2A;  n0A = m0A; n1A = m1A; n2A = m2A;
        f0B = n0B; f1B = n1B; f2B = n2B;  n0B = m0B; n1B = m1B; n2B = m2B;
    }
    {   // chunk 510 (steps 2040..2043)
        float4 ovA, ovB;
        ovA.x = XA * ICS; ovB.x = XB * ICS;
        STEP2(f0A.x, f0A.y, f0A.z, f0A.w,  f0B.x, f0B.y, f0B.z, f0B.w);
        ovA.y = XA * ICS; ovB.y = XB * ICS;
        STEP2(f0A.w, f1A.x, f1A.y, f1A.z,  f0B.w, f1B.x, f1B.y, f1B.z);
        ovA.z = XA * ICS; ovB.z = XB * ICS;
        STEP2(f1A.z, f1A.w, f2A.x, f2A.y,  f1B.z, f1B.w, f2B.x, f2B.y);
        ovA.w = XA * ICS; ovB.w = XB * ICS;
        *reinterpret_cast<float4*>(xcA + 4 * 510) = ovA;
        *reinterpret_cast<float4*>(xcB + 4 * 510) = ovB;
        STEP2(f2A.y, f2A.z, f2A.w, n0A.x,  f2B.y, f2B.z, f2B.w, n0B.x);
        f0A = n0A; f1A = n1A; f2A = n2A;
        f0B = n0B; f1B = n1B; f2B = n2B;
    }
    {   // chunk 511 (steps 2044..2046 -> X(2045..2047))
        float4 ovA, ovB;
        ovA.x = XA * ICS; ovB.x = XB * ICS;
        STEP2(f0A.x, f0A.y, f0A.z, f0A.w,  f0B.x, f0B.y, f0B.z, f0B.w);
        ovA.y = XA * ICS; ovB.y = XB * ICS;
        STEP2(f0A.w, f1A.x, f1A.y, f1A.z,  f0B.w, f1B.x, f1B.y, f1B.z);
        ovA.z = XA * ICS; ovB.z = XB * ICS;
        STEP2(f1A.z, f1A.w, f2A.x, f2A.y,  f1B.z, f1B.w, f2B.x, f2B.y);
        ovA.w = XA * ICS; ovB.w = XB * ICS;
        *reinterpret_cast<float4*>(xcA + 4 * 511) = ovA;
        *reinterpret_cast<float4*>(xcB + 4 * 511) = ovB;
    }
#undef STEP2
}

// ---------------- readout: out = sigmoid(x @ Wn^T + bn) @ Wl^T + bl --------
// Weights read directly from global (uniform per j -> s_load, scalar pipe).
__global__ __launch_bounds__(256) void out_kernel(
    const float* __restrict__ xs, const float* __restrict__ Wn,
    const float* __restrict__ bn, const float* __restrict__ Wl,
    const float* __restrict__ bl, float* __restrict__ out)
{
    int lt = threadIdx.x;
    long long tid = (long long)blockIdx.x * 256 + lt;   // tid = b*T + t
    float c0 = xs[tid];
    float c1 = xs[(long long)BB * TT + tid];
    float c2 = xs[(long long)2 * BB * TT + tid];
    float cs0 = c0 * -NL2E, cs1 = c1 * -NL2E, cs2 = c2 * -NL2E;
    float acc = 0.0f;
    #pragma unroll 8
    for (int j = 0; j < NHI; j++) {
        float zs = fmaf(Wn[j * 3], cs0,
                   fmaf(Wn[j * 3 + 1], cs1,
                   fmaf(Wn[j * 3 + 2], cs2, bn[j] * -NL2E)));
        acc = fmaf(Wl[j], sig_pre(zs), acc);
    }
    out[tid] = acc + bl[0];
}

extern "C" void kernel_launch(void* const* d_in, const int* in_sizes, int n_in,
                              void* d_out, int out_size, void* d_ws, size_t ws_size,
                              hipStream_t stream) {
    const float* u    = (const float*)d_in[0];
    const float* Wni  = (const float*)d_in[1];
    const float* bni  = (const float*)d_in[2];
    const float* Wli  = (const float*)d_in[3];
    const float* bli  = (const float*)d_in[4];
    const float* tau  = (const float*)d_in[5];
    const float* Wn   = (const float*)d_in[6];
    const float* bn   = (const float*)d_in[7];
    const float* Wl   = (const float*)d_in[8];
    const float* bl   = (const float*)d_in[9];
    float* out = (float*)d_out;

    float* r3 = (float*)d_ws;                          // B*T*3 floats (24 MB)
    float* xs = r3 + (size_t)3 * BB * TT;              // [3][B][T] (24 MB)

    precompute_r<<<(BB * 33) / 4, 256, 0, stream>>>(u, Wni, bni, Wli, bli, tau, r3);
    scan_kernel<<<(BB * 4 / 2) / 64, 64, 0, stream>>>(r3, xs);
    out_kernel<<<(BB * TT) / 256, 256, 0, stream>>>(xs, Wn, bn, Wl, bl, out);
}

// Round 9
// 416.048 us; speedup vs baseline: 1.6279x; 1.4201x over previous
//
#include <hip/hip_runtime.h>

#define BB 1024
#define TT 2048
#define NIN 8
#define NHI 64

#define CS 2.8853900817779268f      /* 2*log2(e) */
#define NL2E 1.4426950408889634f    /* log2(e) */
#define DELTA (40.94f / 2047.0f)

template<int CTRL>
__device__ __forceinline__ float qperm(float x) {
    int r = __builtin_amdgcn_mov_dpp(__float_as_int(x), CTRL, 0xF, 0xF, true);
    return __int_as_float(r);
}

// ---------------- precompute g = h*r records [b][s][{gg,ga,gc}] -------------
// Weights read directly from global (uniform per j -> s_load, scalar pipe).
// Shared-exp across the 3 stage points (e1=e0*edz, e2=e1*edz) and ONE rcp for
// all 3 sigmoids via the product trick: sig_i = (prod_{k!=i} a_k) * rcp(D).
__global__ __launch_bounds__(256) void precompute_r(
    const float* __restrict__ u, const float* __restrict__ Wni,
    const float* __restrict__ bni, const float* __restrict__ Wli,
    const float* __restrict__ bli, const float* __restrict__ tau,
    float* __restrict__ r3)
{
    int lt = threadIdx.x;
    int lane = lt & 63;
    long long gw = (long long)blockIdx.x * 4 + (lt >> 6);   // 1024*33 waves
    int b = (int)(gw / 33);
    int chunk = (int)(gw % 33);
    int s = chunk * 63 + lane;
    int sc = s < TT ? s : TT - 1;

    const float4* up4 = reinterpret_cast<const float4*>(u + ((long long)b * TT + sc) * NIN);
    float4 uA = up4[0], uB = up4[1];

    float d0 = 0.f, d1 = 0.f, d2 = 0.f;
    #pragma unroll 8
    for (int j = 0; j < NHI; j++) {
        const float* wj = Wni + j * NIN;          // uniform -> scalar loads
        float z = bni[j];
        z = fmaf(wj[0], uA.x, z); z = fmaf(wj[1], uA.y, z);
        z = fmaf(wj[2], uA.z, z); z = fmaf(wj[3], uA.w, z);
        z = fmaf(wj[4], uB.x, z); z = fmaf(wj[5], uB.y, z);
        z = fmaf(wj[6], uB.z, z); z = fmaf(wj[7], uB.w, z);
        float zn = __shfl_down(z, 1);
        float dz = zn - z;
        float e0  = __builtin_amdgcn_exp2f(z * -NL2E);
        float edz = __builtin_amdgcn_exp2f(dz * (-NL2E / 3.0f));
        float e1 = e0 * edz;
        float e2 = e1 * edz;
        float a0 = 1.0f + e0, a1 = 1.0f + e1, a2 = 1.0f + e2;
        float P12 = a1 * a2;
        float rD = __builtin_amdgcn_rcpf(a0 * P12);
        float P02 = a0 * a2;
        float P01 = a0 * a1;
        float wr = Wli[j] * rD;
        d0 = fmaf(wr, P12, d0);
        d1 = fmaf(wr, P02, d1);
        d2 = fmaf(wr, P01, d2);
    }
    float base = tau[0] + bli[0];
    float g0 = DELTA * __builtin_amdgcn_exp2f((base + d0) * -NL2E);
    float g1 = DELTA * __builtin_amdgcn_exp2f((base + d1) * -NL2E);
    float g2 = DELTA * __builtin_amdgcn_exp2f((base + d2) * -NL2E);

    if (s < TT) {
        float* p = r3 + ((long long)b * TT + s) * 3;
        p[0] = g0;
        if (lane < 63 && s < TT - 1) { p[1] = g1; p[2] = g2; }
    }
}

// ---------------- sequential RK4 scan: one b per quad, lane = component -----
// Round-6 structure (proven 296 us): 4096 threads, 64-thr blocks, 1 chain per
// quad. Scaled state X = CS*x; records hold g = h*r. Per-stage chain:
// exp2 -> add1 -> rcp -> dpp -> fma -> fma. Stores raw X ([3][B][T]); the
// readout folds the conversion (X * -0.5 == -log2e * x, exact).
__global__ __launch_bounds__(64) void scan_kernel(
    const float* __restrict__ r3, float* __restrict__ xs)
{
    int gt = blockIdx.x * 64 + threadIdx.x;     // 4096 threads
    int b = gt >> 2;
    int l = gt & 3;

    const float4* rp = reinterpret_cast<const float4*>(r3 + (long long)b * TT * 3);
    int comp = (l == 3) ? 1 : l;
    float* xc = xs + (long long)comp * BB * TT + (long long)b * TT;

    bool is2 = (l == 2);
    float cA = is2 ? 40.0f * CS : -2.0f * CS;
    float cB = is2 ? -20.0f * CS : 0.0f;
    float Kl = is2 ? -10.0f * CS : CS;

    float X = (l == 0) ? 0.4736f * CS : (is2 ? 1.8497f * CS : 0.8745f * CS);

#define STEP(G1v, G2v, G3v, G4v) do { \
    float g1 = (G1v), g2 = (G2v), g3 = (G3v); \
    float q  = g1 * (1.0f / 3.0f); \
    float g4_8 = (G4v) * 0.125f; \
    float cA1 = q * cA,    cB1 = q * cB; \
    float cA2 = g2 * cA,   cB2 = g2 * cB; \
    float cA3 = g3 * cA,   cB3 = g3 * cB; \
    float cA4 = g4_8 * cA, cB4 = g4_8 * cB; \
    /* stage 1 */ \
    float e1 = __builtin_amdgcn_exp2f(X); \
    float rho1 = __builtin_amdgcn_rcpf(1.0f + e1); \
    float KmX = Kl - X; \
    float pb2 = fmaf(q, KmX, X); \
    float p11 = qperm<0x89>(rho1), p21 = qperm<0x10>(rho1); \
    float S2 = fmaf(cA1, p11, fmaf(cB1, p21, pb2)); \
    float V1 = fmaf(cA, p11, cB * p21); \
    float W1 = V1 + KmX; \
    /* stage 2 */ \
    float e2 = __builtin_amdgcn_exp2f(S2); \
    float rho2 = __builtin_amdgcn_rcpf(1.0f + e2); \
    float KmS2 = Kl - S2; \
    float pb3 = fmaf(g2, KmS2, fmaf(-q, W1, X)); \
    float p12 = qperm<0x89>(rho2), p22 = qperm<0x10>(rho2); \
    float S3 = fmaf(cA2, p12, fmaf(cB2, p22, pb3)); \
    float V2 = fmaf(cA, p12, cB * p22); \
    float W2 = V2 + KmS2; \
    /* stage 3 */ \
    float e3 = __builtin_amdgcn_exp2f(S3); \
    float rho3 = __builtin_amdgcn_rcpf(1.0f + e3); \
    float KmS3 = Kl - S3; \
    float pb4 = fmaf(g3, KmS3, fmaf(-g2, W2, fmaf(g1, W1, X))); \
    float p13 = qperm<0x89>(rho3), p23 = qperm<0x10>(rho3); \
    float S4 = fmaf(cA3, p13, fmaf(cB3, p23, pb4)); \
    float V3 = fmaf(cA, p13, cB * p23); \
    float W3 = V3 + KmS3; \
    /* stage 4 */ \
    float e4 = __builtin_amdgcn_exp2f(S4); \
    float rho4 = __builtin_amdgcn_rcpf(1.0f + e4); \
    float KmS4 = Kl - S4; \
    float t3 = fmaf(3.0f * g3, W3, fmaf(3.0f * g2, W2, g1 * W1)); \
    float pbX = fmaf(g4_8, KmS4, fmaf(0.125f, t3, X)); \
    float p14 = qperm<0x89>(rho4), p24 = qperm<0x10>(rho4); \
    X = fmaf(cA4, p14, fmaf(cB4, p24, pbX)); \
} while (0)

    float4 f0 = rp[0], f1 = rp[1], f2 = rp[2];
    float4 n0 = rp[3], n1 = rp[4], n2 = rp[5];

    for (int j = 0; j < 510; j++) {
        float4 m0 = rp[3 * j + 6], m1 = rp[3 * j + 7], m2 = rp[3 * j + 8];
        float4 ov;
        ov.x = X;
        STEP(f0.x, f0.y, f0.z, f0.w);  ov.y = X;
        STEP(f0.w, f1.x, f1.y, f1.z);  ov.z = X;
        STEP(f1.z, f1.w, f2.x, f2.y);  ov.w = X;
        *reinterpret_cast<float4*>(xc + 4 * j) = ov;
        STEP(f2.y, f2.z, f2.w, n0.x);
        f0 = n0; f1 = n1; f2 = n2;
        n0 = m0; n1 = m1; n2 = m2;
    }
    {   // chunk 510 (steps 2040..2043)
        float4 ov;
        ov.x = X;
        STEP(f0.x, f0.y, f0.z, f0.w);  ov.y = X;
        STEP(f0.w, f1.x, f1.y, f1.z);  ov.z = X;
        STEP(f1.z, f1.w, f2.x, f2.y);  ov.w = X;
        *reinterpret_cast<float4*>(xc + 4 * 510) = ov;
        STEP(f2.y, f2.z, f2.w, n0.x);
        f0 = n0; f1 = n1; f2 = n2;
    }
    {   // chunk 511 (steps 2044..2046 -> X(2045..2047))
        float4 ov;
        ov.x = X;
        STEP(f0.x, f0.y, f0.z, f0.w);  ov.y = X;
        STEP(f0.w, f1.x, f1.y, f1.z);  ov.z = X;
        STEP(f1.z, f1.w, f2.x, f2.y);  ov.w = X;
        *reinterpret_cast<float4*>(xc + 4 * 511) = ov;
    }
#undef STEP
}

// ---------------- readout: out = sigmoid(x @ Wn^T + bn) @ Wl^T + bl --------
// xs holds X = CS*x, so the sigmoid pre-scale is X * -0.5 (exact).
// Adjacent j's share one rcp via the product trick (trans/j: 2 -> 1.5).
__global__ __launch_bounds__(256) void out_kernel(
    const float* __restrict__ xs, const float* __restrict__ Wn,
    const float* __restrict__ bn, const float* __restrict__ Wl,
    const float* __restrict__ bl, float* __restrict__ out)
{
    int lt = threadIdx.x;
    long long tid = (long long)blockIdx.x * 256 + lt;   // tid = b*T + t
    float cs0 = xs[tid] * -0.5f;
    float cs1 = xs[(long long)BB * TT + tid] * -0.5f;
    float cs2 = xs[(long long)2 * BB * TT + tid] * -0.5f;
    float acc = 0.0f;
    #pragma unroll 8
    for (int j = 0; j < NHI; j += 2) {
        float za = fmaf(Wn[3 * j],     cs0,
                   fmaf(Wn[3 * j + 1], cs1,
                   fmaf(Wn[3 * j + 2], cs2, bn[j] * -NL2E)));
        float zb = fmaf(Wn[3 * j + 3], cs0,
                   fmaf(Wn[3 * j + 4], cs1,
                   fmaf(Wn[3 * j + 5], cs2, bn[j + 1] * -NL2E)));
        float ea = __builtin_amdgcn_exp2f(za);
        float eb = __builtin_amdgcn_exp2f(zb);
        float aa = 1.0f + ea, ab = 1.0f + eb;
        float rD = __builtin_amdgcn_rcpf(aa * ab);
        float wra = Wl[j] * rD, wrb = Wl[j + 1] * rD;
        acc = fmaf(wra, ab, acc);   // Wl[j]   * sig(za)
        acc = fmaf(wrb, aa, acc);   // Wl[j+1] * sig(zb)
    }
    out[tid] = acc + bl[0];
}

extern "C" void kernel_launch(void* const* d_in, const int* in_sizes, int n_in,
                              void* d_out, int out_size, void* d_ws, size_t ws_size,
                              hipStream_t stream) {
    const float* u    = (const float*)d_in[0];
    const float* Wni  = (const float*)d_in[1];
    const float* bni  = (const float*)d_in[2];
    const float* Wli  = (const float*)d_in[3];
    const float* bli  = (const float*)d_in[4];
    const float* tau  = (const float*)d_in[5];
    const float* Wn   = (const float*)d_in[6];
    const float* bn   = (const float*)d_in[7];
    const float* Wl   = (const float*)d_in[8];
    const float* bl   = (const float*)d_in[9];
    float* out = (float*)d_out;

    float* r3 = (float*)d_ws;                          // B*T*3 floats (24 MB)
    float* xs = r3 + (size_t)3 * BB * TT;              // [3][B][T] (24 MB)

    precompute_r<<<(BB * 33) / 4, 256, 0, stream>>>(u, Wni, bni, Wli, bli, tau, r3);
    scan_kernel<<<(BB * 4) / 64, 64, 0, stream>>>(r3, xs);
    out_kernel<<<(BB * TT) / 256, 256, 0, stream>>>(xs, Wn, bn, Wl, bl, out);
}

// Round 11
// 397.446 us; speedup vs baseline: 1.7040x; 1.0468x over previous
//
#include <hip/hip_runtime.h>

#define BB 1024
#define TT 2048
#define NIN 8
#define NHI 64

#define CS 2.8853900817779268f      /* 2*log2(e) */
#define NL2E 1.4426950408889634f    /* log2(e) */
#define DELTA (40.94f / 2047.0f)

typedef float v2f __attribute__((ext_vector_type(2)));

__device__ __forceinline__ v2f vfma(v2f a, v2f b, v2f c) {
    return __builtin_elementwise_fma(a, b, c);
}

template<int CTRL>
__device__ __forceinline__ float qperm(float x) {
    int r = __builtin_amdgcn_mov_dpp(__float_as_int(x), CTRL, 0xF, 0xF, true);
    return __int_as_float(r);
}

// ---------------- precompute g = h*r records [b][s][{gg,ga,gc}] -------------
// Each thread processes TWO batches (b, b+512) at the same s as a float2 lane
// pair -> v_pk_fma_f32 halves VALU instruction count. Weights are wave-uniform
// splats (scalar pipe / op_sel); u pairs packed once before the j-loop.
__global__ __launch_bounds__(256) void precompute_r(
    const float* __restrict__ u, const float* __restrict__ Wni,
    const float* __restrict__ bni, const float* __restrict__ Wli,
    const float* __restrict__ bli, const float* __restrict__ tau,
    float* __restrict__ r3)
{
    int lt = threadIdx.x;
    int lane = lt & 63;
    int gw = blockIdx.x * 4 + (lt >> 6);        // 512*33 = 16896 waves
    int b = gw / 33;                            // 0..511
    int chunk = gw % 33;
    int s = chunk * 63 + lane;
    int sc = s < TT ? s : TT - 1;
    int b2 = b + 512;

    const float4* upA = reinterpret_cast<const float4*>(u + ((long long)b  * TT + sc) * NIN);
    const float4* upB = reinterpret_cast<const float4*>(u + ((long long)b2 * TT + sc) * NIN);
    float4 A0 = upA[0], A1 = upA[1];
    float4 B0 = upB[0], B1 = upB[1];
    v2f u0 = {A0.x, B0.x}, u1 = {A0.y, B0.y}, u2 = {A0.z, B0.z}, u3 = {A0.w, B0.w};
    v2f u4 = {A1.x, B1.x}, u5 = {A1.y, B1.y}, u6 = {A1.z, B1.z}, u7 = {A1.w, B1.w};

    v2f d0 = {0.f, 0.f}, d1 = {0.f, 0.f}, d2 = {0.f, 0.f};
    #pragma unroll 8
    for (int j = 0; j < NHI; j++) {
        const float* wj = Wni + j * NIN;        // uniform -> scalar loads
        float bj = bni[j];
        v2f z = {bj, bj};
        z = vfma((v2f){wj[0], wj[0]}, u0, z);
        z = vfma((v2f){wj[1], wj[1]}, u1, z);
        z = vfma((v2f){wj[2], wj[2]}, u2, z);
        z = vfma((v2f){wj[3], wj[3]}, u3, z);
        z = vfma((v2f){wj[4], wj[4]}, u4, z);
        z = vfma((v2f){wj[5], wj[5]}, u5, z);
        z = vfma((v2f){wj[6], wj[6]}, u6, z);
        z = vfma((v2f){wj[7], wj[7]}, u7, z);
        v2f zn;
        zn.x = __shfl_down(z.x, 1);
        zn.y = __shfl_down(z.y, 1);
        v2f dz = zn - z;
        v2f zc  = z  * (v2f){-NL2E, -NL2E};
        v2f dzc = dz * (v2f){-NL2E / 3.0f, -NL2E / 3.0f};
        v2f e0, edz;
        e0.x  = __builtin_amdgcn_exp2f(zc.x);
        e0.y  = __builtin_amdgcn_exp2f(zc.y);
        edz.x = __builtin_amdgcn_exp2f(dzc.x);
        edz.y = __builtin_amdgcn_exp2f(dzc.y);
        v2f e1 = e0 * edz;
        v2f e2 = e1 * edz;
        v2f q0 = e0 + 1.0f, q1 = e1 + 1.0f, q2 = e2 + 1.0f;
        v2f P12 = q1 * q2;
        v2f Dn = q0 * P12;
        v2f rD;
        rD.x = __builtin_amdgcn_rcpf(Dn.x);
        rD.y = __builtin_amdgcn_rcpf(Dn.y);
        v2f P02 = q0 * q2;
        v2f P01 = q0 * q1;
        float wl = Wli[j];
        v2f wr = rD * (v2f){wl, wl};
        d0 = vfma(wr, P12, d0);
        d1 = vfma(wr, P02, d1);
        d2 = vfma(wr, P01, d2);
    }
    float base = tau[0] + bli[0];
    float g0a = DELTA * __builtin_amdgcn_exp2f((base + d0.x) * -NL2E);
    float g1a = DELTA * __builtin_amdgcn_exp2f((base + d1.x) * -NL2E);
    float g2a = DELTA * __builtin_amdgcn_exp2f((base + d2.x) * -NL2E);
    float g0b = DELTA * __builtin_amdgcn_exp2f((base + d0.y) * -NL2E);
    float g1b = DELTA * __builtin_amdgcn_exp2f((base + d1.y) * -NL2E);
    float g2b = DELTA * __builtin_amdgcn_exp2f((base + d2.y) * -NL2E);

    if (s < TT) {
        float* pA = r3 + ((long long)b  * TT + s) * 3;
        float* pB = r3 + ((long long)b2 * TT + s) * 3;
        pA[0] = g0a;
        pB[0] = g0b;
        if (lane < 63 && s < TT - 1) {
            pA[1] = g1a; pA[2] = g2a;
            pB[1] = g1b; pB[2] = g2b;
        }
    }
}

// ---------------- sequential RK4 scan: one b per quad, lane = component -----
// Round-9 verbatim (proven 284 us). Scaled state X = CS*x; records hold
// g = h*r. Per-stage chain: exp2 -> add1 -> rcp -> dpp -> fma -> fma.
// Stores raw X ([3][B][T]); readout folds the conversion (X*-0.5 = -log2e*x).
__global__ __launch_bounds__(64) void scan_kernel(
    const float* __restrict__ r3, float* __restrict__ xs)
{
    int gt = blockIdx.x * 64 + threadIdx.x;     // 4096 threads
    int b = gt >> 2;
    int l = gt & 3;

    const float4* rp = reinterpret_cast<const float4*>(r3 + (long long)b * TT * 3);
    int comp = (l == 3) ? 1 : l;
    float* xc = xs + (long long)comp * BB * TT + (long long)b * TT;

    bool is2 = (l == 2);
    float cA = is2 ? 40.0f * CS : -2.0f * CS;
    float cB = is2 ? -20.0f * CS : 0.0f;
    float Kl = is2 ? -10.0f * CS : CS;

    float X = (l == 0) ? 0.4736f * CS : (is2 ? 1.8497f * CS : 0.8745f * CS);

#define STEP(G1v, G2v, G3v, G4v) do { \
    float g1 = (G1v), g2 = (G2v), g3 = (G3v); \
    float q  = g1 * (1.0f / 3.0f); \
    float g4_8 = (G4v) * 0.125f; \
    float cA1 = q * cA,    cB1 = q * cB; \
    float cA2 = g2 * cA,   cB2 = g2 * cB; \
    float cA3 = g3 * cA,   cB3 = g3 * cB; \
    float cA4 = g4_8 * cA, cB4 = g4_8 * cB; \
    /* stage 1 */ \
    float e1 = __builtin_amdgcn_exp2f(X); \
    float rho1 = __builtin_amdgcn_rcpf(1.0f + e1); \
    float KmX = Kl - X; \
    float pb2 = fmaf(q, KmX, X); \
    float p11 = qperm<0x89>(rho1), p21 = qperm<0x10>(rho1); \
    float S2 = fmaf(cA1, p11, fmaf(cB1, p21, pb2)); \
    float V1 = fmaf(cA, p11, cB * p21); \
    float W1 = V1 + KmX; \
    /* stage 2 */ \
    float e2 = __builtin_amdgcn_exp2f(S2); \
    float rho2 = __builtin_amdgcn_rcpf(1.0f + e2); \
    float KmS2 = Kl - S2; \
    float pb3 = fmaf(g2, KmS2, fmaf(-q, W1, X)); \
    float p12 = qperm<0x89>(rho2), p22 = qperm<0x10>(rho2); \
    float S3 = fmaf(cA2, p12, fmaf(cB2, p22, pb3)); \
    float V2 = fmaf(cA, p12, cB * p22); \
    float W2 = V2 + KmS2; \
    /* stage 3 */ \
    float e3 = __builtin_amdgcn_exp2f(S3); \
    float rho3 = __builtin_amdgcn_rcpf(1.0f + e3); \
    float KmS3 = Kl - S3; \
    float pb4 = fmaf(g3, KmS3, fmaf(-g2, W2, fmaf(g1, W1, X))); \
    float p13 = qperm<0x89>(rho3), p23 = qperm<0x10>(rho3); \
    float S4 = fmaf(cA3, p13, fmaf(cB3, p23, pb4)); \
    float V3 = fmaf(cA, p13, cB * p23); \
    float W3 = V3 + KmS3; \
    /* stage 4 */ \
    float e4 = __builtin_amdgcn_exp2f(S4); \
    float rho4 = __builtin_amdgcn_rcpf(1.0f + e4); \
    float KmS4 = Kl - S4; \
    float t3 = fmaf(3.0f * g3, W3, fmaf(3.0f * g2, W2, g1 * W1)); \
    float pbX = fmaf(g4_8, KmS4, fmaf(0.125f, t3, X)); \
    float p14 = qperm<0x89>(rho4), p24 = qperm<0x10>(rho4); \
    X = fmaf(cA4, p14, fmaf(cB4, p24, pbX)); \
} while (0)

    float4 f0 = rp[0], f1 = rp[1], f2 = rp[2];
    float4 n0 = rp[3], n1 = rp[4], n2 = rp[5];

    for (int j = 0; j < 510; j++) {
        float4 m0 = rp[3 * j + 6], m1 = rp[3 * j + 7], m2 = rp[3 * j + 8];
        float4 ov;
        ov.x = X;
        STEP(f0.x, f0.y, f0.z, f0.w);  ov.y = X;
        STEP(f0.w, f1.x, f1.y, f1.z);  ov.z = X;
        STEP(f1.z, f1.w, f2.x, f2.y);  ov.w = X;
        *reinterpret_cast<float4*>(xc + 4 * j) = ov;
        STEP(f2.y, f2.z, f2.w, n0.x);
        f0 = n0; f1 = n1; f2 = n2;
        n0 = m0; n1 = m1; n2 = m2;
    }
    {   // chunk 510 (steps 2040..2043)
        float4 ov;
        ov.x = X;
        STEP(f0.x, f0.y, f0.z, f0.w);  ov.y = X;
        STEP(f0.w, f1.x, f1.y, f1.z);  ov.z = X;
        STEP(f1.z, f1.w, f2.x, f2.y);  ov.w = X;
        *reinterpret_cast<float4*>(xc + 4 * 510) = ov;
        STEP(f2.y, f2.z, f2.w, n0.x);
        f0 = n0; f1 = n1; f2 = n2;
    }
    {   // chunk 511 (steps 2044..2046 -> X_2045..X_2047)
        float4 ov;
        ov.x = X;
        STEP(f0.x, f0.y, f0.z, f0.w);  ov.y = X;
        STEP(f0.w, f1.x, f1.y, f1.z);  ov.z = X;
        STEP(f1.z, f1.w, f2.x, f2.y);  ov.w = X;
        *reinterpret_cast<float4*>(xc + 4 * 511) = ov;
    }
#undef STEP
}

// ---------------- readout: out = sigmoid(x @ Wn^T + bn) @ Wl^T + bl --------
// Each thread handles TWO time points (tid, tid + BT/2) as a float2 pair ->
// pk_fma on the z dot; one rcp per (j, t-pair) via the product trick.
// xs holds X = CS*x, so the sigmoid pre-scale is X * -0.5 (exact).
__global__ __launch_bounds__(256) void out_kernel(
    const float* __restrict__ xs, const float* __restrict__ Wn,
    const float* __restrict__ bn, const float* __restrict__ Wl,
    const float* __restrict__ bl, float* __restrict__ out)
{
    const long long HALF = (long long)BB * TT / 2;
    int lt = threadIdx.x;
    long long tid = (long long)blockIdx.x * 256 + lt;   // 0 .. B*T/2-1
    long long tid2 = tid + HALF;

    v2f cs0 = { xs[tid],                        xs[tid2] };
    v2f cs1 = { xs[(long long)BB * TT + tid],   xs[(long long)BB * TT + tid2] };
    v2f cs2 = { xs[(long long)2 * BB * TT + tid], xs[(long long)2 * BB * TT + tid2] };
    cs0 = cs0 * -0.5f;
    cs1 = cs1 * -0.5f;
    cs2 = cs2 * -0.5f;

    v2f acc = {0.f, 0.f};
    #pragma unroll 8
    for (int j = 0; j < NHI; j++) {
        float w0 = Wn[3 * j], w1 = Wn[3 * j + 1], w2 = Wn[3 * j + 2];
        float bz = bn[j] * -NL2E;
        v2f z = vfma((v2f){w0, w0}, cs0,
                vfma((v2f){w1, w1}, cs1,
                vfma((v2f){w2, w2}, cs2, (v2f){bz, bz})));
        float ea = __builtin_amdgcn_exp2f(z.x);
        float eb = __builtin_amdgcn_exp2f(z.y);
        float qa = 1.0f + ea, qb = 1.0f + eb;
        float rD = __builtin_amdgcn_rcpf(qa * qb);
        float wr = Wl[j] * rD;
        v2f sw = {qb, qa};                       // sig(z.x)=qb*rD, sig(z.y)=qa*rD
        acc = vfma((v2f){wr, wr}, sw, acc);
    }
    out[tid]  = acc.x + bl[0];
    out[tid2] = acc.y + bl[0];
}

extern "C" void kernel_launch(void* const* d_in, const int* in_sizes, int n_in,
                              void* d_out, int out_size, void* d_ws, size_t ws_size,
                              hipStream_t stream) {
    const float* u    = (const float*)d_in[0];
    const float* Wni  = (const float*)d_in[1];
    const float* bni  = (const float*)d_in[2];
    const float* Wli  = (const float*)d_in[3];
    const float* bli  = (const float*)d_in[4];
    const float* tau  = (const float*)d_in[5];
    const float* Wn   = (const float*)d_in[6];
    const float* bn   = (const float*)d_in[7];
    const float* Wl   = (const float*)d_in[8];
    const float* bl   = (const float*)d_in[9];
    float* out = (float*)d_out;

    float* r3 = (float*)d_ws;                          // B*T*3 floats (24 MB)
    float* xs = r3 + (size_t)3 * BB * TT;              // [3][B][T] (24 MB)

    precompute_r<<<(512 * 33) / 4, 256, 0, stream>>>(u, Wni, bni, Wli, bli, tau, r3);
    scan_kernel<<<(BB * 4) / 64, 64, 0, stream>>>(r3, xs);
    out_kernel<<<(BB * TT / 2) / 256, 256, 0, stream>>>(xs, Wn, bn, Wl, bl, out);
}